// Round 6
// baseline (240.919 us; speedup 1.0000x reference)
//
#include <hip/hip_runtime.h>
#include <hip/hip_fp16.h>

#define N_NODES 100000
#define N_EDGES 1600000
#define MSG 16
#define HID 16
#define NT 8
#define NC 32
#define PREP_N 800000   // = N*HID/2 packed half2 words = N*MSG/2 m2 words

typedef _Float16 v2h __attribute__((ext_vector_type(2)));

union H2U {
    v2h h;
    unsigned int u;
};

// ---------------------------------------------------------------------------
// Prep: feat (f32) -> feat16 (packed half2), and zero the m2 accumulator.
// Both arrays happen to be exactly PREP_N uints.
// ---------------------------------------------------------------------------
__global__ __launch_bounds__(256) void ggnn_prep(
    const float* __restrict__ feat,
    unsigned int* __restrict__ feat16,
    unsigned int* __restrict__ m2) {
    int i = blockIdx.x * 256 + threadIdx.x;
    if (i >= PREP_N) return;
    float2 f = reinterpret_cast<const float2*>(feat)[i];
    H2U p;
    p.h[0] = (_Float16)f.x;
    p.h[1] = (_Float16)f.y;
    feat16[i] = p.u;
    m2[i] = 0u;
}

// ---------------------------------------------------------------------------
// Edge kernel: 16 lanes per edge, grid-stride. Lane j computes
//   msg[j] = sum_k A[t][j][k] * h16[src][k]
// A staged once per block in LDS as As[t][k][j] (lane-linear writes ->
// conflict-free; transposed global reads are L1-absorbed, 8 KB one-time).
// K-loop rotated per wave-group -> 2-way LDS banks (free).
// h gathered from the 3.2 MB fp16 feature mirror (fits per-XCD L2).
// Accumulate via packed fp16 atomics (12.8M fire-and-forget ops).
// ---------------------------------------------------------------------------
__global__ __launch_bounds__(256) void ggnn_edge(
    const int* __restrict__ src,
    const int* __restrict__ dst,
    const int* __restrict__ etype,
    const unsigned int* __restrict__ feat16,
    const float* __restrict__ edge_table,
    unsigned int* __restrict__ m2) {
    __shared__ float As[NT * MSG * HID];   // As[t*256 + k*16 + j], 8 KB
    int tid = threadIdx.x;
    #pragma unroll
    for (int i = tid; i < NT * MSG * HID; i += 256) {
        int t = i >> 8;
        int k = (i >> 4) & 15;
        int j = i & 15;
        As[i] = edge_table[t * 256 + j * 16 + k];   // write linear, read scattered
    }
    __syncthreads();

    int grp = tid >> 4;          // 0..15 edge-slot within block
    int j = tid & 15;            // output column
    int g = grp & 3;             // group within wave (bank-rotation phase)
    int stride = gridDim.x * 16;

    for (int e = blockIdx.x * 16 + grp; e < N_EDGES; e += stride) {
        int s = src[e];
        int t = etype[e];
        H2U hp;
        hp.u = feat16[s * 8 + (j >> 1)];     // 32B per edge-group, L2-resident
        float hj = (float)hp.h[j & 1];

        const float* At = As + t * 256;
        float acc = 0.f;
        #pragma unroll
        for (int k0 = 0; k0 < 16; ++k0) {
            int k = (k0 + g) & 15;           // rotate: 2-way banks (free)
            float hk = __shfl(hj, k, 16);
            acc += At[k * 16 + j] * hk;
        }

        int d = dst[e];
        float a = __shfl(acc, 2 * (j & 7), 16);
        float b = __shfl(acc, 2 * (j & 7) + 1, 16);
        if (j < 8) {
            H2U p;
            p.h[0] = (_Float16)a;
            p.h[1] = (_Float16)b;
            __builtin_amdgcn_global_atomic_fadd_v2f16(
                reinterpret_cast<v2h*>(m2 + (size_t)d * 8 + j), p.h);
        }
    }
}

// ---------------------------------------------------------------------------
// Node kernel: GRU cell + output projection. One thread per node; weights
// are wave-uniform -> scalar loads. m read back as fp16 -> f32; h in f32.
// ---------------------------------------------------------------------------
__device__ __forceinline__ float fast_sigmoid(float x) {
    return 1.f / (1.f + __expf(-x));
}
__device__ __forceinline__ float fast_tanh(float x) {
    return 2.f / (1.f + __expf(-2.f * x)) - 1.f;
}

__global__ __launch_bounds__(256) void ggnn_node(
    const float* __restrict__ feat,
    const unsigned int* __restrict__ m2,
    const float* __restrict__ W_ih,
    const float* __restrict__ W_hh,
    const float* __restrict__ b_ih,
    const float* __restrict__ b_hh,
    const float* __restrict__ W_out,
    const float* __restrict__ b_out,
    float* __restrict__ out) {
    int n = blockIdx.x * 256 + threadIdx.x;
    if (n >= N_NODES) return;

    float mv[MSG], h[HID];
    {
        const uint4* mu = reinterpret_cast<const uint4*>(m2 + (size_t)n * 8);
        uint4 a = mu[0], b = mu[1];
        unsigned int w[8] = {a.x, a.y, a.z, a.w, b.x, b.y, b.z, b.w};
        #pragma unroll
        for (int i = 0; i < 8; ++i) {
            H2U hh;
            hh.u = w[i];
            mv[2 * i]     = (float)hh.h[0];
            mv[2 * i + 1] = (float)hh.h[1];
        }
        const float4* f4 = reinterpret_cast<const float4*>(feat + (size_t)n * HID);
        #pragma unroll
        for (int q = 0; q < 4; ++q) {
            float4 v = f4[q];
            h[q * 4 + 0] = v.x; h[q * 4 + 1] = v.y;
            h[q * 4 + 2] = v.z; h[q * 4 + 3] = v.w;
        }
    }

    float srz[2 * HID];
    for (int g = 0; g < 2 * HID; ++g) {
        float ai = 0.f, ah = 0.f;
        const float* wi = W_ih + g * MSG;
        const float* wh = W_hh + g * HID;
        #pragma unroll
        for (int k = 0; k < HID; ++k) {
            ai += wi[k] * mv[k];
            ah += wh[k] * h[k];
        }
        srz[g] = ai + ah + b_ih[g] + b_hh[g];
    }
    float i_n[HID], h_n[HID];
    #pragma unroll
    for (int j = 0; j < HID; ++j) {
        int g = 2 * HID + j;
        float ai = b_ih[g], ah = b_hh[g];
        const float* wi = W_ih + g * MSG;
        const float* wh = W_hh + g * HID;
        #pragma unroll
        for (int k = 0; k < HID; ++k) {
            ai += wi[k] * mv[k];
            ah += wh[k] * h[k];
        }
        i_n[j] = ai;
        h_n[j] = ah;
    }

    float hn[HID];
    #pragma unroll
    for (int j = 0; j < HID; ++j) {
        float r = fast_sigmoid(srz[j]);
        float z = fast_sigmoid(srz[HID + j]);
        float nn = fast_tanh(i_n[j] + r * h_n[j]);
        hn[j] = (1.f - z) * nn + z * h[j];
    }

    float4* op = reinterpret_cast<float4*>(out + (size_t)n * NC);
    #pragma unroll
    for (int c4 = 0; c4 < NC / 4; ++c4) {
        float4 o;
        float* oo = &o.x;
        #pragma unroll
        for (int cc = 0; cc < 4; ++cc) {
            int c = c4 * 4 + cc;
            float acc = b_out[c];
            const float* wo = W_out + c * HID;
            #pragma unroll
            for (int k = 0; k < HID; ++k) acc += wo[k] * hn[k];
            oo[cc] = acc;
        }
        op[c4] = o;
    }
}

extern "C" void kernel_launch(void* const* d_in, const int* in_sizes, int n_in,
                              void* d_out, int out_size, void* d_ws, size_t ws_size,
                              hipStream_t stream) {
    const float* feat       = (const float*)d_in[0];
    const int*   src        = (const int*)d_in[1];
    const int*   dst        = (const int*)d_in[2];
    const int*   etype      = (const int*)d_in[3];
    const float* edge_table = (const float*)d_in[4];
    const float* W_ih       = (const float*)d_in[5];
    const float* W_hh       = (const float*)d_in[6];
    const float* b_ih       = (const float*)d_in[7];
    const float* b_hh       = (const float*)d_in[8];
    const float* W_out      = (const float*)d_in[9];
    const float* b_out      = (const float*)d_in[10];
    float* out = (float*)d_out;

    // workspace: m2 [N*8] uint (3.2 MB), feat16 [N*8] uint (3.2 MB)
    unsigned int* m2     = (unsigned int*)d_ws;
    unsigned int* feat16 = m2 + (size_t)N_NODES * 8;

    int pblocks = (PREP_N + 255) / 256;                  // 3125
    ggnn_prep<<<pblocks, 256, 0, stream>>>(feat, feat16, m2);

    ggnn_edge<<<2048, 256, 0, stream>>>(src, dst, etype, feat16, edge_table, m2);

    int nblocks = (N_NODES + 255) / 256;                 // 391
    ggnn_node<<<nblocks, 256, 0, stream>>>(feat, m2, W_ih, W_hh, b_ih, b_hh,
                                           W_out, b_out, out);
}